// Round 12
// baseline (251.816 us; speedup 1.0000x reference)
//
#include <hip/hip_runtime.h>
#include <hip/hip_bf16.h>
#include <math.h>

typedef __hip_bfloat16 bf16;
typedef __attribute__((ext_vector_type(8))) short bf16x8;
typedef __attribute__((ext_vector_type(4))) short bf16x4;
typedef __attribute__((ext_vector_type(4))) float f32x4;

__device__ __forceinline__ float b2f(bf16 v) { return __bfloat162float(v); }
__device__ __forceinline__ bf16  f2b(float v) { return __float2bfloat16(v); }
__device__ __forceinline__ float s2f(short v) { return __uint_as_float(((unsigned)(unsigned short)v) << 16); }

// async global->LDS, 16B/lane. LDS dest = wave-uniform base + lane*16.
__device__ __forceinline__ void gl_lds16(const void* g, void* l)
{
    __builtin_amdgcn_global_load_lds(
        (const __attribute__((address_space(1))) void*)g,
        (__attribute__((address_space(3))) void*)l, 16, 0, 0);
}

// ---------------------------------------------------------------------------
// ALL converts fused in one launch. r12: dtype detection is computed LOCALLY
// per block (reads x[0..2047] only — never written, race-free, L2-hot), which
// removes the serial detect_dtype launch. Block 6419 publishes the flag for
// gemm_proj128 (4 kernel boundaries later -> visibility guaranteed).
// blocks [0,4096): x convert; [4096,5120): sr_w; [5120,5129): dw;
// [5129,5139): small vectors; [5139,6419): six weight transposes; 6419: gbuf.
// ---------------------------------------------------------------------------
struct AllArgs {
    const void* x; bf16* cx;
    const void* srw;  bf16* srwT;
    const void* dww;  bf16* dwT;
    const void* psrc[10]; bf16* pdst[10]; int pn[10];
    const void* wsrc[6]; bf16* wdst[6]; int wN[6]; int wblkoff[7];
    float* gbuf;
    int* flag;
};
__global__ void convert_all(AllArgs a)
{
    __shared__ int cnt;
    int blk = blockIdx.x, t = threadIdx.x;
    if (t == 0) cnt = 0;
    __syncthreads();
    {
        const unsigned* w = (const unsigned*)a.x;
        int sane = 0;
        for (int i = t; i < 2048; i += 256) {
            unsigned lo = (w[i] & 0xFFFFu) << 16;
            float v = __uint_as_float(lo);
            float av = fabsf(v);
            if (v == 0.f || (av > 1e-8f && av < 1e4f)) sane++;
        }
        atomicAdd(&cnt, sane);
    }
    __syncthreads();
    int fl = (cnt < 1640) ? 1 : 0;   // 1 = fp32 inputs, 0 = bf16

    if (blk < 4096) {
        int i = blk * 256 + t;   // 1048576 quads
        if (fl) {
            float4 v = ((const float4*)a.x)[i];
            bf16 tmp[4];
            tmp[0] = f2b(v.x); tmp[1] = f2b(v.y); tmp[2] = f2b(v.z); tmp[3] = f2b(v.w);
            *(bf16x4*)&a.cx[i * 4] = *(bf16x4*)tmp;
        } else {
            ((bf16x4*)a.cx)[i] = ((const bf16x4*)a.x)[i];
        }
    } else if (blk < 5120) {
        // sr_w (256co, 256ci, 2, 2) -> WT[co*1024 + (e*256+ci)]
        int o = (blk - 4096) * 256 + t;
        int co = o >> 10, kg = o & 1023;
        int e = kg >> 8, ci = kg & 255;
        int si = co * 1024 + ci * 4 + e;
        float v = fl ? ((const float*)a.srw)[si] : s2f(((const short*)a.srw)[si]);
        a.srwT[o] = f2b(v);
    } else if (blk < 5129) {
        // lepe_conv_w (256c,9) -> dwT[k*256+c]
        int o = (blk - 5120) * 256 + t;
        if (o >= 2304) return;
        int k = o >> 8, c = o & 255;
        float v = fl ? ((const float*)a.dww)[c * 9 + k] : s2f(((const short*)a.dww)[c * 9 + k]);
        a.dwT[o] = f2b(v);
    } else if (blk < 5139) {
        int bi = blk - 5129;
        int n = a.pn[bi];
        const void* s = a.psrc[bi];
        bf16* d = a.pdst[bi];
        for (int i = t; i < n; i += 256)
            d[i] = fl ? f2b(((const float*)s)[i]) : f2b(s2f(((const short*)s)[i]));
    } else if (blk < 6419) {
        int wblk = blk - 5139;
        int ti = 0;
        while (wblk >= a.wblkoff[ti + 1]) ++ti;
        int o = (wblk - a.wblkoff[ti]) * 256 + t;
        int n = o >> 8, k = o & 255;
        int N = a.wN[ti];
        float v = fl ? ((const float*)a.wsrc[ti])[k * N + n]
                     : s2f(((const short*)a.wsrc[ti])[k * N + n]);
        a.wdst[ti][o] = f2b(v);
    } else {
        for (int i = t; i < 4096; i += 256) a.gbuf[i] = 0.f;
        if (t == 0) *a.flag = fl;   // publish for gemm_proj128
    }
}

// ---------------------------------------------------------------------------
// qkv GEMM body, 128x128 tile (r6-validated). A from cx (bf16) into padded
// As[128][40]; B (bf16 WT) staged via global_load_lds into XOR-swizzled 8KB.
// softmax scale folded into q1/q2 outputs.
// ---------------------------------------------------------------------------
__device__ __forceinline__ void qkv_body(
    int bx, int by, char* smem,
    const bf16* __restrict__ A, const bf16* __restrict__ WT, const bf16* __restrict__ bias,
    bf16* __restrict__ Cl, bf16* __restrict__ Cq1, bf16* __restrict__ Cq2, bf16* __restrict__ Ckv2)
{
    bf16 (*As)[40] = (bf16(*)[40])smem;    // 128x40 = 10240 B
    char* Bs = smem + 10240;               // 8192 B, swizzled
    int t = threadIdx.x;
    int m0 = bx * 128, ybase = by * 128;
    int w = t >> 6, l = t & 63, lane16 = l & 15, quad = l >> 4;
    int wr = w >> 1, wc = w & 1;
    int srow = t >> 1, scol = (t & 1) * 16;

    // B-side gl_lds mapping (two 1KB chunks per wave)
    int oph0 = w * 2048 + l * 16;
    int oph1 = oph0 + 1024;
    int olog0 = oph0 ^ (((oph0 >> 7) & 3) << 4);
    int olog1 = oph1 ^ (((oph1 >> 7) & 3) << 4);
    int row0 = olog0 >> 6, ce0 = (olog0 & 63) >> 1;
    int row1 = olog1 >> 6, ce1 = (olog1 & 63) >> 1;
    char* bsb0 = Bs + w * 2048; char* bsb1 = bsb0 + 1024;

    f32x4 acc[4][4] = {};
    for (int k0 = 0; k0 < 256; k0 += 32) {
        *(bf16x8*)&As[srow][scol]     = *(const bf16x8*)&A[(size_t)(m0 + srow) * 256 + k0 + scol];
        *(bf16x8*)&As[srow][scol + 8] = *(const bf16x8*)&A[(size_t)(m0 + srow) * 256 + k0 + scol + 8];
        gl_lds16(&WT[(size_t)(ybase + row0) * 256 + k0 + ce0], bsb0);
        gl_lds16(&WT[(size_t)(ybase + row1) * 256 + k0 + ce1], bsb1);
        __syncthreads();
        bf16x8 a[4], b[4];
        #pragma unroll
        for (int i = 0; i < 4; ++i) {
            a[i] = *(const bf16x8*)&As[wr * 64 + i * 16 + lane16][quad * 8];
            int rb = wc * 64 + i * 16 + lane16;
            int ob = (rb << 6) + (quad << 4);
            ob ^= (((ob >> 7) & 3) << 4);
            b[i] = *(const bf16x8*)(Bs + ob);
        }
        #pragma unroll
        for (int i = 0; i < 4; ++i)
            #pragma unroll
            for (int j = 0; j < 4; ++j)
                acc[i][j] = __builtin_amdgcn_mfma_f32_16x16x32_bf16(a[i], b[j], acc[i][j], 0, 0, 0);
        __syncthreads();
    }
    bf16* C; int N, cbase;
    if (ybase < 256)      { C = Cl;   N = 256; cbase = ybase; }
    else if (ybase < 384) { C = Cq1;  N = 128; cbase = ybase - 256; }
    else if (ybase < 512) { C = Cq2;  N = 128; cbase = ybase - 384; }
    else                  { C = Ckv2; N = 256; cbase = ybase - 512; }
    float mult = (ybase >= 256 && ybase < 512) ? 0.17677669529663687f : 1.f;
    #pragma unroll
    for (int j = 0; j < 4; ++j) {
        int gcol = ybase + wc * 64 + j * 16 + lane16;
        float bv = b2f(bias[gcol]);
        int col = cbase + wc * 64 + j * 16 + lane16;
        #pragma unroll
        for (int i = 0; i < 4; ++i)
            #pragma unroll
            for (int r = 0; r < 4; ++r) {
                int row = m0 + wr * 64 + i * 16 + quad * 4 + r;
                C[(size_t)row * N + col] = f2b((acc[i][j][r] + bv) * mult);
            }
    }
}

// sr conv as MFMA GEMM with gathered A rows. M=4096, N=256, K=1024.
__device__ __forceinline__ void sr_body(
    int bx, int by, char* smem,
    const bf16* __restrict__ x, const bf16* __restrict__ WT,
    const bf16* __restrict__ bias, bf16* __restrict__ C)
{
    bf16 (*As)[40] = (bf16(*)[40])smem;            // 64x40
    bf16 (*Bs)[40] = (bf16(*)[40])(smem + 5120);   // 64x40
    int t = threadIdx.x;
    int m0 = bx * 64, n0 = by * 64;
    int w = t >> 6, l = t & 63, lane16 = l & 15, quad = l >> 4;
    int sr = t >> 2, sc = (t & 3) * 8;
    int brow = m0 + sr;
    int b = brow >> 10, p = brow & 1023;
    int pi = p >> 5, pj = p & 31;
    f32x4 acc[4] = {};
    for (int k0 = 0; k0 < 1024; k0 += 32) {
        int kg = k0 + sc;
        int e = kg >> 8, ci = kg & 255;
        int di = e >> 1, dj = e & 1;
        int n = (2 * pi + di) * 64 + 2 * pj + dj;
        *(bf16x8*)&As[sr][sc] = *(const bf16x8*)&x[(size_t)((b << 12) + n) * 256 + ci];
        *(bf16x8*)&Bs[sr][sc] = *(const bf16x8*)&WT[(size_t)(n0 + sr) * 1024 + kg];
        __syncthreads();
        bf16x8 a = *(const bf16x8*)&As[w * 16 + lane16][quad * 8];
        #pragma unroll
        for (int ct = 0; ct < 4; ++ct) {
            bf16x8 bb = *(const bf16x8*)&Bs[ct * 16 + lane16][quad * 8];
            acc[ct] = __builtin_amdgcn_mfma_f32_16x16x32_bf16(a, bb, acc[ct], 0, 0, 0);
        }
        __syncthreads();
    }
    #pragma unroll
    for (int ct = 0; ct < 4; ++ct) {
        int col = n0 + ct * 16 + lane16;
        float bv = b2f(bias[col]);
        #pragma unroll
        for (int r = 0; r < 4; ++r) {
            int row = m0 + w * 16 + quad * 4 + r;
            C[(size_t)row * 256 + col] = f2b(acc[ct][r] + bv);
        }
    }
}

// fuseA: blocks where (idx&3)<3 -> qkv (768), (idx&3)==3 -> sr (256).
__global__ __launch_bounds__(256) void fuseA(
    const bf16* __restrict__ cx, const bf16* __restrict__ wTqkv, const bf16* __restrict__ bcat,
    bf16* __restrict__ Cl, bf16* __restrict__ Cq1, bf16* __restrict__ Cq2, bf16* __restrict__ Ckv2,
    const bf16* __restrict__ srwT, const bf16* __restrict__ srb, bf16* __restrict__ xs_pre)
{
    __shared__ __align__(16) char smem[18432];
    int idx = blockIdx.x;
    int g = idx >> 2, r3 = idx & 3;
    if (r3 < 3) {
        int q = g * 3 + r3;           // 0..767
        qkv_body(q & 127, q >> 7, smem, cx, wTqkv, bcat, Cl, Cq1, Cq2, Ckv2);
    } else {
        sr_body(g & 63, g >> 6, smem, cx, srwT, srb, xs_pre);
    }
}

// ---------------------------------------------------------------------------
// layernorm+gelu body, one wave per row (4 ch/lane).
// ---------------------------------------------------------------------------
__device__ __forceinline__ void ln_body(
    int blk,
    const bf16* __restrict__ xin, const bf16* __restrict__ nw,
    const bf16* __restrict__ nb, bf16* __restrict__ xout)
{
    int w = threadIdx.x >> 6, lane = threadIdx.x & 63;
    int r = blk * 4 + w;
    bf16x4 xv = *(const bf16x4*)&xin[(size_t)r * 256 + lane * 4];
    float v[4];
    #pragma unroll
    for (int j = 0; j < 4; ++j) v[j] = s2f(xv[j]);
    float s = v[0] + v[1] + v[2] + v[3];
    #pragma unroll
    for (int o = 1; o <= 32; o <<= 1) s += __shfl_xor(s, o);
    float mean = s * (1.f / 256.f);
    float ss = 0.f;
    #pragma unroll
    for (int j = 0; j < 4; ++j) { float d = v[j] - mean; ss += d * d; }
    #pragma unroll
    for (int o = 1; o <= 32; o <<= 1) ss += __shfl_xor(ss, o);
    float inv = rsqrtf(ss * (1.f / 256.f) + 1e-5f);
    bf16x4 wv = *(const bf16x4*)&nw[lane * 4];
    bf16x4 bv = *(const bf16x4*)&nb[lane * 4];
    bf16 ov[4];
    #pragma unroll
    for (int j = 0; j < 4; ++j) {
        float y = (v[j] - mean) * inv * s2f(wv[j]) + s2f(bv[j]);
        ov[j] = f2b(0.5f * y * (1.f + erff(y * 0.70710678118654752f)));
    }
    *(bf16x4*)&xout[(size_t)r * 256 + lane * 4] = *(bf16x4*)ov;
}

// depthwise 3x3 body, paired rows: one thread -> 8 channels x 2 tokens.
__device__ __forceinline__ void dw_body(
    int blk,
    const bf16* __restrict__ lin, const bf16* __restrict__ dwT,
    const bf16* __restrict__ bias, bf16* __restrict__ out)
{
    int tid = blk * 256 + threadIdx.x;   // 262144
    int c0 = (tid & 31) * 8;
    int j  = (tid >> 5) & 63;
    int i  = ((tid >> 11) & 31) * 2;
    int b  = tid >> 16;
    float acc0[8], acc1[8];
    bf16x8 bv = *(const bf16x8*)&bias[c0];
    #pragma unroll
    for (int q = 0; q < 8; ++q) { acc0[q] = s2f(bv[q]); acc1[q] = s2f(bv[q]); }
    bf16x8 wv[3][3];
    #pragma unroll
    for (int di = 0; di < 3; ++di)
        #pragma unroll
        for (int dj = 0; dj < 3; ++dj)
            wv[di][dj] = *(const bf16x8*)&dwT[(di * 3 + dj) * 256 + c0];
    #pragma unroll
    for (int r = -1; r <= 2; ++r) {
        int ii = i + r;
        if (ii < 0 || ii > 63) continue;
        #pragma unroll
        for (int dj = 0; dj < 3; ++dj) {
            int jj = j + dj - 1;
            if (jj < 0 || jj > 63) continue;
            bf16x8 xv = *(const bf16x8*)&lin[(size_t)((b << 12) + ii * 64 + jj) * 256 + c0];
            if (r <= 1) {
                bf16x8 w0 = wv[r + 1][dj];
                #pragma unroll
                for (int q = 0; q < 8; ++q) acc0[q] += s2f(xv[q]) * s2f(w0[q]);
            }
            if (r >= 0) {
                bf16x8 w1 = wv[r][dj];
                #pragma unroll
                for (int q = 0; q < 8; ++q) acc1[q] += s2f(xv[q]) * s2f(w1[q]);
            }
        }
    }
    bf16 ov[8];
    #pragma unroll
    for (int q = 0; q < 8; ++q) ov[q] = f2b(acc0[q]);
    *(bf16x8*)&out[(size_t)((b << 12) + i * 64 + j) * 256 + c0] = *(bf16x8*)ov;
    #pragma unroll
    for (int q = 0; q < 8; ++q) ov[q] = f2b(acc1[q]);
    *(bf16x8*)&out[(size_t)((b << 12) + (i + 1) * 64 + j) * 256 + c0] = *(bf16x8*)ov;
}

// fuseB: even blocks -> ln_gelu (1024), odd -> dwconv (1024).
__global__ __launch_bounds__(256) void fuseB(
    const bf16* __restrict__ xs_pre, const bf16* __restrict__ nw,
    const bf16* __restrict__ nb, bf16* __restrict__ xs,
    const bf16* __restrict__ lepe_lin, const bf16* __restrict__ dwT,
    const bf16* __restrict__ dwb, bf16* __restrict__ lepe)
{
    int idx = blockIdx.x;
    if ((idx & 1) == 0) ln_body(idx >> 1, xs_pre, nw, nb, xs);
    else                dw_body(idx >> 1, lepe_lin, dwT, dwb, lepe);
}

// ---------------------------------------------------------------------------
// kv1 GEMM body: xs[4096,256] @ kv1_w + b; K-half -> k1, V-half -> v1T.
// smem: As @0 (5120), Bs @5120 (5120).
// ---------------------------------------------------------------------------
__device__ __forceinline__ void kv1_body(
    int bx, int by, char* smem,
    const bf16* __restrict__ A, const bf16* __restrict__ WT, const bf16* __restrict__ bias,
    bf16* __restrict__ k1, bf16* __restrict__ v1T)
{
    bf16 (*As)[40] = (bf16(*)[40])smem;
    bf16 (*Bs)[40] = (bf16(*)[40])(smem + 5120);
    int t = threadIdx.x;
    int m0 = bx * 64, n0 = by * 64;
    int w = t >> 6, l = t & 63, lane16 = l & 15, quad = l >> 4;
    int sr = t >> 2, sc = (t & 3) * 8;
    f32x4 acc[4] = {};
    for (int k0 = 0; k0 < 256; k0 += 32) {
        *(bf16x8*)&As[sr][sc] = *(const bf16x8*)&A[(size_t)(m0 + sr) * 256 + k0 + sc];
        *(bf16x8*)&Bs[sr][sc] = *(const bf16x8*)&WT[(size_t)(n0 + sr) * 256 + k0 + sc];
        __syncthreads();
        bf16x8 a = *(const bf16x8*)&As[w * 16 + lane16][quad * 8];
        #pragma unroll
        for (int ct = 0; ct < 4; ++ct) {
            bf16x8 b = *(const bf16x8*)&Bs[ct * 16 + lane16][quad * 8];
            acc[ct] = __builtin_amdgcn_mfma_f32_16x16x32_bf16(a, b, acc[ct], 0, 0, 0);
        }
        __syncthreads();
    }
    #pragma unroll
    for (int ct = 0; ct < 4; ++ct) {
        int col = n0 + ct * 16 + lane16;
        float bv = b2f(bias[col]);
        #pragma unroll
        for (int r = 0; r < 4; ++r) {
            int row = m0 + w * 16 + quad * 4 + r;
            float val = acc[ct][r] + bv;
            int bb = row >> 10, key = row & 1023;
            if (col < 128) {
                k1[(size_t)row * 128 + col] = f2b(val);
            } else {
                int h = (col - 128) >> 5, ch = (col - 128) & 31;
                v1T[(size_t)((bb * 4 + h) * 32 + ch) * 1024 + key] = f2b(val);
            }
        }
    }
}

// ---------------------------------------------------------------------------
// Branch-2 windowed attention body (r8-validated). smem: PT2 @0 (5120),
// lmw @5120 (64).
// ---------------------------------------------------------------------------
__device__ __forceinline__ void attn2_body(
    int blk, char* smem,
    const bf16* __restrict__ q2, const bf16* __restrict__ kv2,
    bf16* __restrict__ attn_out, float* __restrict__ lm)
{
    bf16* PT2 = (bf16*)smem;
    float* lmw = (float*)(smem + 5120);
    int t = threadIdx.x;
    int b = blk >> 8, win = blk & 255;
    int wi = win >> 4, wj = win & 15;
    int h = t >> 6, l = t & 63, lane16 = l & 15, quad = l >> 4;

    if (t < 16) lmw[t] = 0.f;
    bf16* ptt = PT2 + h * 16 * 40;
    {
        bf16 zz[4] = {};
        *(bf16x4*)&ptt[lane16 * 40 + 16 + quad * 4] = *(bf16x4*)zz;
    }
    __syncthreads();

    size_t base = (size_t)(b * 4096);
    int r0 = wi * 4, c0w = wj * 4;
    int tq = (r0 + (lane16 >> 2)) * 64 + c0w + (lane16 & 3);

    bf16x8 qa = *(const bf16x8*)&q2[(base + tq) * 128 + h * 32 + quad * 8];
    bf16x8 kf = *(const bf16x8*)&kv2[(base + tq) * 256 + h * 32 + quad * 8];

    f32x4 z = {0.f, 0.f, 0.f, 0.f};
    f32x4 sT = __builtin_amdgcn_mfma_f32_16x16x32_bf16(kf, qa, z, 0, 0, 0);
    float sv[4];
    #pragma unroll
    for (int r = 0; r < 4; ++r) sv[r] = sT[r];
    float mx = fmaxf(fmaxf(sv[0], sv[1]), fmaxf(sv[2], sv[3]));
    mx = fmaxf(mx, __shfl_xor(mx, 16));
    mx = fmaxf(mx, __shfl_xor(mx, 32));
    float p[4], lsum = 0.f;
    #pragma unroll
    for (int r = 0; r < 4; ++r) { p[r] = __expf(sv[r] - mx); lsum += p[r]; }
    lsum += __shfl_xor(lsum, 16);
    lsum += __shfl_xor(lsum, 32);
    float rl = 1.f / lsum;
    bf16 pk[4];
    #pragma unroll
    for (int r = 0; r < 4; ++r) { p[r] *= rl; pk[r] = f2b(p[r]); }
    *(bf16x4*)&ptt[lane16 * 40 + quad * 4] = *(bf16x4*)pk;

    bf16x8 vf0 = {}, vf1 = {};
    if (quad < 2) {
        #pragma unroll
        for (int jj = 0; jj < 8; ++jj) {
            int key = quad * 8 + jj;
            int tk = (r0 + (key >> 2)) * 64 + c0w + (key & 3);
            const short* vp = (const short*)&kv2[(base + tk) * 256 + 128 + h * 32];
            vf0[jj] = vp[lane16];
            vf1[jj] = vp[16 + lane16];
        }
    }
    bf16x8 pf = *(const bf16x8*)&ptt[lane16 * 40 + quad * 8];
    f32x4 o0 = __builtin_amdgcn_mfma_f32_16x16x32_bf16(vf0, pf, z, 0, 0, 0);
    f32x4 o1 = __builtin_amdgcn_mfma_f32_16x16x32_bf16(vf1, pf, z, 0, 0, 0);
    {
        bf16 ov0[4], ov1[4];
        #pragma unroll
        for (int r = 0; r < 4; ++r) { ov0[r] = f2b(o0[r]); ov1[r] = f2b(o1[r]); }
        bf16* op = attn_out + (base + tq) * 256 + 128 + h * 32;
        *(bf16x4*)&op[quad * 4]      = *(bf16x4*)ov0;
        *(bf16x4*)&op[16 + quad * 4] = *(bf16x4*)ov1;
    }

    #pragma unroll
    for (int r = 0; r < 4; ++r) {
        float c = p[r];
        c += __shfl_xor(c, 1);
        c += __shfl_xor(c, 2);
        c += __shfl_xor(c, 4);
        c += __shfl_xor(c, 8);
        if (lane16 == 0) atomicAdd(&lmw[quad * 4 + r], c);
    }
    __syncthreads();
    if (t < 16) {
        int nk = (r0 + (t >> 2)) * 64 + c0w + (t & 3);
        lm[(b << 12) + nk] = lmw[t] * (1.f / 64.f);
    }
}

// fuseC2: blocks [0,256) = kv1 GEMM (dispatch-first), [256,1280) = attn2.
// Independent ops (disjoint buffers), both short/high-occupancy — no
// residency-generation trap (combined LDS 10.3KB -> 8 blocks/CU, 2048 cap).
__global__ __launch_bounds__(256) void fuseC2(
    const bf16* __restrict__ xs, const bf16* __restrict__ kv1_wT,
    const bf16* __restrict__ kv1b, bf16* __restrict__ k1, bf16* __restrict__ v1T,
    const bf16* __restrict__ q2, const bf16* __restrict__ kv2,
    bf16* __restrict__ attn_out, float* __restrict__ lm)
{
    __shared__ __align__(16) char smem[10304];
    int idx = blockIdx.x;
    if (idx < 256) kv1_body(idx & 63, idx >> 6, smem, xs, kv1_wT, kv1b, k1, v1T);
    else           attn2_body(idx - 256, smem, q2, kv2, attn_out, lm);
}

// ---------------------------------------------------------------------------
// Branch-1 attention — EXACT r2/r3-measured structure (62.8-63.0 us, x4):
// 1024 blocks x 256 thr, K/V LDS dbuf, 1 barrier/tile, __expf (scale folded
// into q1), PTT[4][16][72]. LDS 32256 B. DO NOT MODIFY: PTT stride 68,
// exp2 variants, shuffle-exchange, big-phase, and all fusions regressed.
// ---------------------------------------------------------------------------
__global__ __launch_bounds__(256) void attn1_split(
    const bf16* __restrict__ q1, const bf16* __restrict__ k1,
    const bf16* __restrict__ v1T, bf16* __restrict__ attn_out, float* __restrict__ g)
{
    __shared__ bf16 Kt[2][64][40];      // double-buffered K tile (key-major)
    __shared__ bf16 Vt[2][32][68];      // double-buffered V^T tile (ch-major)
    __shared__ bf16 PTT[4][16][72];     // per-wave P^T strip [q][k]
    __shared__ float gp[1024];

    int t = threadIdx.x;
    int blk = blockIdx.x;
    int qc = blk & 63, h = (blk >> 6) & 3, b = blk >> 8;
    int n0 = qc * 64;
    int w = t >> 6, l = t & 63, lane16 = l & 15, quad = l >> 4;

    const bf16* Kbase = k1 + (size_t)b * 1024 * 128 + 32 * h;
    const bf16* Vbase = v1T + (size_t)((b * 4 + h) * 32) * 1024;
    bf16x8 qa = *(const bf16x8*)&q1[(size_t)(b * 4096 + n0 + 16 * w + lane16) * 128 + 32 * h + quad * 8];

    for (int i = t; i < 1024; i += 256) gp[i] = 0.f;

    int sr = t >> 2, sc = (t & 3) * 8;      // K staging: 64 rows x 32
    int vrow = t >> 3, vcol = (t & 7) * 8;  // V staging: 32 rows x 64
    bf16* ptt = &PTT[w][0][0];

    // stage tile 0
    *(bf16x8*)&Kt[0][sr][sc]     = *(const bf16x8*)&Kbase[(size_t)sr * 128 + sc];
    *(bf16x8*)&Vt[0][vrow][vcol] = *(const bf16x8*)&Vbase[(size_t)vrow * 1024 + vcol];
    __syncthreads();

    float lacc = 0.f;
    f32x4 oT0 = {}, oT1 = {};

    // ---- sweep 1 over 16 key tiles: 1 barrier/tile, prefetch overlap ----
    for (int ktl = 0; ktl < 16; ++ktl) {
        int cur = ktl & 1;
        bf16x8 knext, vnext;
        if (ktl < 15) {
            knext = *(const bf16x8*)&Kbase[(size_t)((ktl + 1) * 64 + sr) * 128 + sc];
            vnext = *(const bf16x8*)&Vbase[(size_t)vrow * 1024 + (ktl + 1) * 64 + vcol];
        }
        bf16x8 kf[4];
        #pragma unroll
        for (int st = 0; st < 4; ++st)
            kf[st] = *(const bf16x8*)&Kt[cur][st * 16 + lane16][quad * 8];
        #pragma unroll
        for (int st = 0; st < 4; ++st) {
            f32x4 z = {0.f, 0.f, 0.f, 0.f};
            f32x4 sT = __builtin_amdgcn_mfma_f32_16x16x32_bf16(kf[st], qa, z, 0, 0, 0);
            bf16 pk[4];
            #pragma unroll
            for (int r = 0; r < 4; ++r) {
                float p = __expf(sT[r]);
                lacc += p;
                pk[r] = f2b(p);
            }
            *(bf16x4*)&ptt[lane16 * 72 + st * 16 + quad * 4] = *(bf16x4*)pk;
        }
        #pragma unroll
        for (int kh = 0; kh < 2; ++kh) {
            bf16x8 pf  = *(const bf16x8*)&ptt[lane16 * 72 + kh * 32 + quad * 8];
            bf16x8 vf0 = *(const bf16x8*)&Vt[cur][lane16][kh * 32 + quad * 8];
            bf16x8 vf1 = *(const bf16x8*)&Vt[cur][16 + lane16][kh * 32 + quad * 8];
            oT0 = __builtin_amdgcn_mfma_f32_16x16x32_bf16(vf0, pf, oT0, 0, 0, 0);
            oT1 = __builtin_amdgcn_mfma_f32_16x16x32_bf16(vf1, pf, oT1, 0, 0, 0);
        }
        if (ktl < 15) {
            *(bf16x8*)&Kt[cur ^ 1][sr][sc]     = knext;
            *(bf16x8*)&Vt[cur ^ 1][vrow][vcol] = vnext;
        }
        __syncthreads();
    }

    // l for q = lane16 (sum over quads), then normalize + store O
    lacc += __shfl_xor(lacc, 16);
    lacc += __shfl_xor(lacc, 32);
    float rl = 1.f / lacc;
    {
        bf16 ov0[4], ov1[4];
        #pragma unroll
        for (int r = 0; r < 4; ++r) {
            ov0[r] = f2b(oT0[r] * rl);
            ov1[r] = f2b(oT1[r] * rl);
        }
        size_t ro = (size_t)(b * 4096 + n0 + 16 * w + lane16) * 256 + 32 * h;
        *(bf16x4*)&attn_out[ro + quad * 4]      = *(bf16x4*)ov0;
        *(bf16x4*)&attn_out[ro + 16 + quad * 4] = *(bf16x4*)ov1;
    }

    // rl for q = quad*4+r via in-wave shuffle
    float rlq[4];
    #pragma unroll
    for (int r = 0; r < 4; ++r) rlq[r] = __shfl(rl, quad * 4 + r);

    // ---- sweep 2: g column sums; K re-staged via LDS dbuf (coalesced) ----
    *(bf16x8*)&Kt[0][sr][sc] = *(const bf16x8*)&Kbase[(size_t)sr * 128 + sc];
    __syncthreads();
    for (int ktl = 0; ktl < 16; ++ktl) {
        int cur = ktl & 1;
        bf16x8 knext;
        if (ktl < 15)
            knext = *(const bf16x8*)&Kbase[(size_t)((ktl + 1) * 64 + sr) * 128 + sc];
        bf16x8 kf2[4];
        #pragma unroll
        for (int st = 0; st < 4; ++st)
            kf2[st] = *(const bf16x8*)&Kt[cur][st * 16 + lane16][quad * 8];
        #pragma unroll
        for (int st = 0; st < 4; ++st) {
            f32x4 z = {0.f, 0.f, 0.f, 0.f};
            f32x4 s = __builtin_amdgcn_mfma_f32_16x16x32_bf16(qa, kf2[st], z, 0, 0, 0);
            float cs = 0.f;
            #pragma unroll
            for (int r = 0; r < 4; ++r) cs += __expf(s[r]) * rlq[r];
            cs += __shfl_xor(cs, 16);
            cs += __shfl_xor(cs, 32);
            if (quad == 0) atomicAdd(&gp[ktl * 64 + st * 16 + lane16], cs);
        }
        if (ktl < 15)
            *(bf16x8*)&Kt[cur ^ 1][sr][sc] = knext;
        __syncthreads();
    }

    for (int i = t; i < 1024; i += 256)
        atomicAdd(&g[(b << 10) + i], gp[i] * (1.f / 16384.f));
}

// proj GEMM, 128x128 tile: out = 2*((attn+lepe) @ proj_w + bias). grid (128,3);
// y==2 slice handles the mask combine (blockIdx.x < 64).
__global__ __launch_bounds__(256) void gemm_proj128(
    const bf16* __restrict__ A, const bf16* __restrict__ A2,
    const bf16* __restrict__ WT, const bf16* __restrict__ bias,
    const float* __restrict__ lm, const float* __restrict__ g,
    void* __restrict__ dout, const int* __restrict__ flag)
{
    if (blockIdx.y == 2) {
        if (blockIdx.x >= 64) return;
        int tid = blockIdx.x * 256 + threadIdx.x;   // 16384
        int b = tid >> 12, n = tid & 4095;
        int i = n >> 6, j = n & 63;
        float v = lm[tid] + g[(b << 10) + (i >> 1) * 32 + (j >> 1)];
        size_t o1 = (size_t)4194304 + (b << 12) + i * 64 + j;
        size_t o2 = (size_t)4194304 + 16384 + (b << 12) + j * 64 + i;
        if (*flag) { ((float*)dout)[o1] = v; ((float*)dout)[o2] = v; }
        else       { ((bf16*)dout)[o1] = f2b(v); ((bf16*)dout)[o2] = f2b(v); }
        return;
    }
    __shared__ bf16 As[128][40];
    __shared__ bf16 Bs[128][40];
    int t = threadIdx.x;
    int m0 = blockIdx.x * 128, n0 = blockIdx.y * 128;
    int w = t >> 6, l = t & 63, lane16 = l & 15, quad = l >> 4;
    int wr = w >> 1, wc = w & 1;
    int sr = t >> 1, sc = (t & 1) * 16;
    f32x4 acc[4][4] = {};
    for (int k0 = 0; k0 < 256; k0 += 32) {
        #pragma unroll
        for (int hh = 0; hh < 2; ++hh) {
            bf16x8 va = *(const bf16x8*)&A[(size_t)(m0 + sr) * 256 + k0 + sc + hh * 8];
            bf16x8 vb = *(const bf16x8*)&A2[(size_t)(m0 + sr) * 256 + k0 + sc + hh * 8];
            bf16 tmp[8];
            #pragma unroll
            for (int q = 0; q < 8; ++q) tmp[q] = f2b(s2f(va[q]) + s2f(vb[q]));
            *(bf16x8*)&As[sr][sc + hh * 8] = *(bf16x8*)tmp;
        }
        *(bf16x8*)&Bs[sr][sc]     = *(const bf16x8*)&WT[(size_t)(n0 + sr) * 256 + k0 + sc];
        *(bf16x8*)&Bs[sr][sc + 8] = *(const bf16x8*)&WT[(size_t)(n0 + sr) * 256 + k0 + sc + 8];
        __syncthreads();
        bf16x8 a[4], b[4];
        #pragma unroll
        for (int i = 0; i < 4; ++i) {
            a[i] = *(const bf16x8*)&As[wr * 64 + i * 16 + lane16][quad * 8];
            b[i] = *(const bf16x8*)&Bs[wc * 64 + i * 16 + lane16][quad * 8];
        }
        #pragma unroll
        for (int i = 0; i < 4; ++i)
            #pragma unroll
            for (int j = 0; j < 4; ++j)
                acc[i][j] = __builtin_amdgcn_mfma_f32_16x16x32_bf16(a[i], b[j], acc[i][j], 0, 0, 0);
        __syncthreads();
    }
    #pragma unroll
    for (int j = 0; j < 4; ++j) {
        int col = n0 + wc * 64 + j * 16 + lane16;
        float bv = b2f(bias[col]);
        #pragma unroll
        for (int i = 0; i < 4; ++i)
            #pragma unroll
            for (int r = 0; r < 4; ++r) {
                int row = m0 + wr * 64 + i * 16 + quad * 4 + r;
                float rv = (acc[i][j][r] + bv) * 2.f;
                size_t o = (size_t)row * 256 + col;
                if (*flag) ((float*)dout)[o] = rv;
                else       ((bf16*)dout)[o] = f2b(rv);
            }
    }
}

// ---------------------------------------------------------------------------
extern "C" void kernel_launch(void* const* d_in, const int* in_sizes, int n_in,
                              void* d_out, int out_size, void* d_ws, size_t ws_size,
                              hipStream_t stream)
{
    char* ws = (char*)d_ws;
    size_t off = 0;
    auto alloc = [&](size_t bytes) {
        void* p = ws + off;
        off += (bytes + 255) & ~(size_t)255;
        return p;
    };
    bf16* cx       = (bf16*)alloc((size_t)4194304 * 2);
    bf16* lepe_lin = (bf16*)alloc((size_t)4194304 * 2);   // reused as attn_out
    bf16* attn_out = lepe_lin;
    bf16* lepe     = (bf16*)alloc((size_t)4194304 * 2);
    bf16* q1buf    = (bf16*)alloc((size_t)2097152 * 2);
    bf16* q2buf    = (bf16*)alloc((size_t)2097152 * 2);
    bf16* kv2buf   = (bf16*)alloc((size_t)4194304 * 2);
    bf16* xs_pre   = (bf16*)alloc((size_t)1048576 * 2);   // later reused: k1 + v1T
    bf16* k1buf    = xs_pre;                               // 524288 elems
    bf16* v1Tbuf   = xs_pre + 524288;                      // 524288 elems
    bf16* xs       = (bf16*)alloc((size_t)1048576 * 2);
    bf16* wTqkv    = (bf16*)alloc((size_t)196608 * 2);     // 768 x 256
    bf16* kv1_wT   = (bf16*)alloc(65536 * 2);
    bf16* proj_wT  = (bf16*)alloc(65536 * 2);
    bf16* sr_wT    = (bf16*)alloc(262144 * 2);
    bf16* dwT      = (bf16*)alloc(2304 * 2);
    bf16* bcat     = (bf16*)alloc(768 * 2);
    bf16* ckv1b    = (bf16*)alloc(256 * 2);
    bf16* csrb     = (bf16*)alloc(256 * 2);
    bf16* cnw      = (bf16*)alloc(256 * 2);
    bf16* cnb      = (bf16*)alloc(256 * 2);
    bf16* cpb      = (bf16*)alloc(256 * 2);
    bf16* clcb     = (bf16*)alloc(256 * 2);
    float* gbuf    = (float*)alloc(4096 * 4);
    float* lmbuf   = (float*)alloc(16384 * 4);
    int*   flag    = (int*)alloc(256);

    AllArgs aa;
    aa.x = d_in[0]; aa.cx = cx;
    aa.srw = d_in[13]; aa.srwT = sr_wT;
    aa.dww = d_in[11]; aa.dwT = dwT;
    aa.psrc[0] = d_in[10]; aa.pdst[0] = bcat;       aa.pn[0] = 256;  // lepe_b
    aa.psrc[1] = d_in[2];  aa.pdst[1] = bcat + 256; aa.pn[1] = 128;  // q1_b
    aa.psrc[2] = d_in[6];  aa.pdst[2] = bcat + 384; aa.pn[2] = 128;  // q2_b
    aa.psrc[3] = d_in[8];  aa.pdst[3] = bcat + 512; aa.pn[3] = 256;  // kv2_b
    aa.psrc[4] = d_in[4];  aa.pdst[4] = ckv1b;      aa.pn[4] = 256;
    aa.psrc[5] = d_in[14]; aa.pdst[5] = csrb;       aa.pn[5] = 256;
    aa.psrc[6] = d_in[15]; aa.pdst[6] = cnw;        aa.pn[6] = 256;
    aa.psrc[7] = d_in[16]; aa.pdst[7] = cnb;        aa.pn[7] = 256;
    aa.psrc[8] = d_in[18]; aa.pdst[8] = cpb;        aa.pn[8] = 256;
    aa.psrc[9] = d_in[12]; aa.pdst[9] = clcb;       aa.pn[9] = 256;
    aa.wsrc[0] = d_in[9];  aa.wdst[0] = wTqkv;             aa.wN[0] = 256;
    aa.wsrc[1] = d_in[1];  aa.wdst[1] = wTqkv + 256 * 256; aa.wN[1] = 128;
    aa.wsrc[2] = d_in[5];  aa.wdst[2] = wTqkv + 384 * 256; aa.wN[2] = 128;
    aa.wsrc[3] = d_in[7];  aa.wdst[3] = wTqkv + 512 * 256; aa.wN[3] = 256;
    aa.wsrc[4] = d_in[3];  aa.wdst[4] = kv1_wT;            aa.wN[4] = 256;
    aa.wsrc[5] = d_in[17]; aa.wdst[5] = proj_wT;           aa.wN[5] = 256;
    int bo[7] = {0, 256, 384, 512, 768, 1024, 1280};
    for (int i = 0; i < 7; ++i) aa.wblkoff[i] = bo[i];
    aa.gbuf = gbuf;
    aa.flag = flag;
    // r12: dtype detection folded into convert_all (per-block local compute);
    // the serial 1-block detect_dtype launch is gone.
    convert_all<<<6420, 256, 0, stream>>>(aa);

    // fuseA: qkv projections (768 blocks, gl_lds B staging) + sr conv (256)
    fuseA<<<1024, 256, 0, stream>>>(cx, wTqkv, bcat, lepe_lin, q1buf, q2buf, kv2buf,
                                    sr_wT, csrb, xs_pre);
    // fuseB: ln+gelu (1024) + depthwise conv (1024), interleaved
    fuseB<<<2048, 256, 0, stream>>>(xs_pre, cnw, cnb, xs, lepe_lin, dwT, clcb, lepe);
    // fuseC2: kv1 GEMM (256 blocks) + attn2 (1024 blocks) — independent ops
    fuseC2<<<1280, 256, 0, stream>>>(xs, kv1_wT, ckv1b, k1buf, v1Tbuf,
                                     q2buf, kv2buf, attn_out, lmbuf);
    // attn1: own launch, exact validated structure (never co-schedule)
    attn1_split<<<1024, 256, 0, stream>>>(q1buf, k1buf, v1Tbuf, attn_out, gbuf);
    // projection epilogue (128x128 tile) + fused mask combine (y==2 slice)
    gemm_proj128<<<dim3(128, 3), 256, 0, stream>>>(attn_out, lepe, proj_wT, cpb,
                                                   lmbuf, gbuf, d_out, flag);
}

// Round 13
// 241.717 us; speedup vs baseline: 1.0418x; 1.0418x over previous
//
#include <hip/hip_runtime.h>
#include <hip/hip_bf16.h>
#include <math.h>

typedef __hip_bfloat16 bf16;
typedef __attribute__((ext_vector_type(8))) short bf16x8;
typedef __attribute__((ext_vector_type(4))) short bf16x4;
typedef __attribute__((ext_vector_type(4))) float f32x4;

__device__ __forceinline__ float b2f(bf16 v) { return __bfloat162float(v); }
__device__ __forceinline__ bf16  f2b(float v) { return __float2bfloat16(v); }
__device__ __forceinline__ float s2f(short v) { return __uint_as_float(((unsigned)(unsigned short)v) << 16); }

// async global->LDS, 16B/lane. LDS dest = wave-uniform base + lane*16.
__device__ __forceinline__ void gl_lds16(const void* g, void* l)
{
    __builtin_amdgcn_global_load_lds(
        (const __attribute__((address_space(1))) void*)g,
        (__attribute__((address_space(3))) void*)l, 16, 0, 0);
}

// ---------------------------------------------------------------------------
// Input dtype detection: 1 = fp32 buffers, 0 = bf16 buffers.
// (Kept as its own serial launch: folding it into convert_all was measured
//  SLOWER in r12 — 6420x redundant scans cost more than one tiny launch.)
// ---------------------------------------------------------------------------
__global__ void detect_dtype(const void* x, int* flag)
{
    __shared__ int cnt;
    if (threadIdx.x == 0) cnt = 0;
    __syncthreads();
    const unsigned* w = (const unsigned*)x;
    int sane = 0;
    for (int i = threadIdx.x; i < 2048; i += 256) {
        unsigned lo = (w[i] & 0xFFFFu) << 16;
        float v = __uint_as_float(lo);
        float a = fabsf(v);
        if (v == 0.f || (a > 1e-8f && a < 1e4f)) sane++;
    }
    atomicAdd(&cnt, sane);
    __syncthreads();
    if (threadIdx.x == 0) *flag = (cnt < 1640) ? 1 : 0;
}

// ---------------------------------------------------------------------------
// ALL converts fused in one launch (r6-validated layout).
// ---------------------------------------------------------------------------
struct AllArgs {
    const void* x; bf16* cx;
    const void* srw;  bf16* srwT;
    const void* dww;  bf16* dwT;
    const void* psrc[10]; bf16* pdst[10]; int pn[10];
    const void* wsrc[6]; bf16* wdst[6]; int wN[6]; int wblkoff[7];
    float* gbuf;
};
__global__ void convert_all(AllArgs a, const int* __restrict__ flag)
{
    int blk = blockIdx.x, t = threadIdx.x;
    int fl = *flag;
    if (blk < 4096) {
        int i = blk * 256 + t;   // 1048576 quads
        if (fl) {
            float4 v = ((const float4*)a.x)[i];
            bf16 tmp[4];
            tmp[0] = f2b(v.x); tmp[1] = f2b(v.y); tmp[2] = f2b(v.z); tmp[3] = f2b(v.w);
            *(bf16x4*)&a.cx[i * 4] = *(bf16x4*)tmp;
        } else {
            ((bf16x4*)a.cx)[i] = ((const bf16x4*)a.x)[i];
        }
    } else if (blk < 5120) {
        // sr_w (256co, 256ci, 2, 2) -> WT[co*1024 + (e*256+ci)]
        int o = (blk - 4096) * 256 + t;
        int co = o >> 10, kg = o & 1023;
        int e = kg >> 8, ci = kg & 255;
        int si = co * 1024 + ci * 4 + e;
        float v = fl ? ((const float*)a.srw)[si] : s2f(((const short*)a.srw)[si]);
        a.srwT[o] = f2b(v);
    } else if (blk < 5129) {
        // lepe_conv_w (256c,9) -> dwT[k*256+c]
        int o = (blk - 5120) * 256 + t;
        if (o >= 2304) return;
        int k = o >> 8, c = o & 255;
        float v = fl ? ((const float*)a.dww)[c * 9 + k] : s2f(((const short*)a.dww)[c * 9 + k]);
        a.dwT[o] = f2b(v);
    } else if (blk < 5139) {
        int bi = blk - 5129;
        int n = a.pn[bi];
        const void* s = a.psrc[bi];
        bf16* d = a.pdst[bi];
        for (int i = t; i < n; i += 256)
            d[i] = fl ? f2b(((const float*)s)[i]) : f2b(s2f(((const short*)s)[i]));
    } else if (blk < 6419) {
        int wblk = blk - 5139;
        int ti = 0;
        while (wblk >= a.wblkoff[ti + 1]) ++ti;
        int o = (wblk - a.wblkoff[ti]) * 256 + t;
        int n = o >> 8, k = o & 255;
        int N = a.wN[ti];
        float v = fl ? ((const float*)a.wsrc[ti])[k * N + n]
                     : s2f(((const short*)a.wsrc[ti])[k * N + n]);
        a.wdst[ti][o] = f2b(v);
    } else {
        for (int i = t; i < 4096; i += 256) a.gbuf[i] = 0.f;
    }
}

// ---------------------------------------------------------------------------
// qkv GEMM body, 128x128 tile (r6-validated). A from cx (bf16) into padded
// As[128][40]; B (bf16 WT) staged via global_load_lds into XOR-swizzled 8KB.
// softmax scale folded into q1/q2 outputs.
// ---------------------------------------------------------------------------
__device__ __forceinline__ void qkv_body(
    int bx, int by, char* smem,
    const bf16* __restrict__ A, const bf16* __restrict__ WT, const bf16* __restrict__ bias,
    bf16* __restrict__ Cl, bf16* __restrict__ Cq1, bf16* __restrict__ Cq2, bf16* __restrict__ Ckv2)
{
    bf16 (*As)[40] = (bf16(*)[40])smem;    // 128x40 = 10240 B
    char* Bs = smem + 10240;               // 8192 B, swizzled
    int t = threadIdx.x;
    int m0 = bx * 128, ybase = by * 128;
    int w = t >> 6, l = t & 63, lane16 = l & 15, quad = l >> 4;
    int wr = w >> 1, wc = w & 1;
    int srow = t >> 1, scol = (t & 1) * 16;

    // B-side gl_lds mapping (two 1KB chunks per wave)
    int oph0 = w * 2048 + l * 16;
    int oph1 = oph0 + 1024;
    int olog0 = oph0 ^ (((oph0 >> 7) & 3) << 4);
    int olog1 = oph1 ^ (((oph1 >> 7) & 3) << 4);
    int row0 = olog0 >> 6, ce0 = (olog0 & 63) >> 1;
    int row1 = olog1 >> 6, ce1 = (olog1 & 63) >> 1;
    char* bsb0 = Bs + w * 2048; char* bsb1 = bsb0 + 1024;

    f32x4 acc[4][4] = {};
    for (int k0 = 0; k0 < 256; k0 += 32) {
        *(bf16x8*)&As[srow][scol]     = *(const bf16x8*)&A[(size_t)(m0 + srow) * 256 + k0 + scol];
        *(bf16x8*)&As[srow][scol + 8] = *(const bf16x8*)&A[(size_t)(m0 + srow) * 256 + k0 + scol + 8];
        gl_lds16(&WT[(size_t)(ybase + row0) * 256 + k0 + ce0], bsb0);
        gl_lds16(&WT[(size_t)(ybase + row1) * 256 + k0 + ce1], bsb1);
        __syncthreads();
        bf16x8 a[4], b[4];
        #pragma unroll
        for (int i = 0; i < 4; ++i) {
            a[i] = *(const bf16x8*)&As[wr * 64 + i * 16 + lane16][quad * 8];
            int rb = wc * 64 + i * 16 + lane16;
            int ob = (rb << 6) + (quad << 4);
            ob ^= (((ob >> 7) & 3) << 4);
            b[i] = *(const bf16x8*)(Bs + ob);
        }
        #pragma unroll
        for (int i = 0; i < 4; ++i)
            #pragma unroll
            for (int j = 0; j < 4; ++j)
                acc[i][j] = __builtin_amdgcn_mfma_f32_16x16x32_bf16(a[i], b[j], acc[i][j], 0, 0, 0);
        __syncthreads();
    }
    bf16* C; int N, cbase;
    if (ybase < 256)      { C = Cl;   N = 256; cbase = ybase; }
    else if (ybase < 384) { C = Cq1;  N = 128; cbase = ybase - 256; }
    else if (ybase < 512) { C = Cq2;  N = 128; cbase = ybase - 384; }
    else                  { C = Ckv2; N = 256; cbase = ybase - 512; }
    float mult = (ybase >= 256 && ybase < 512) ? 0.17677669529663687f : 1.f;
    #pragma unroll
    for (int j = 0; j < 4; ++j) {
        int gcol = ybase + wc * 64 + j * 16 + lane16;
        float bv = b2f(bias[gcol]);
        int col = cbase + wc * 64 + j * 16 + lane16;
        #pragma unroll
        for (int i = 0; i < 4; ++i)
            #pragma unroll
            for (int r = 0; r < 4; ++r) {
                int row = m0 + wr * 64 + i * 16 + quad * 4 + r;
                C[(size_t)row * N + col] = f2b((acc[i][j][r] + bv) * mult);
            }
    }
}

// sr conv as MFMA GEMM with gathered A rows. M=4096, N=256, K=1024.
__device__ __forceinline__ void sr_body(
    int bx, int by, char* smem,
    const bf16* __restrict__ x, const bf16* __restrict__ WT,
    const bf16* __restrict__ bias, bf16* __restrict__ C)
{
    bf16 (*As)[40] = (bf16(*)[40])smem;            // 64x40
    bf16 (*Bs)[40] = (bf16(*)[40])(smem + 5120);   // 64x40
    int t = threadIdx.x;
    int m0 = bx * 64, n0 = by * 64;
    int w = t >> 6, l = t & 63, lane16 = l & 15, quad = l >> 4;
    int sr = t >> 2, sc = (t & 3) * 8;
    int brow = m0 + sr;
    int b = brow >> 10, p = brow & 1023;
    int pi = p >> 5, pj = p & 31;
    f32x4 acc[4] = {};
    for (int k0 = 0; k0 < 1024; k0 += 32) {
        int kg = k0 + sc;
        int e = kg >> 8, ci = kg & 255;
        int di = e >> 1, dj = e & 1;
        int n = (2 * pi + di) * 64 + 2 * pj + dj;
        *(bf16x8*)&As[sr][sc] = *(const bf16x8*)&x[(size_t)((b << 12) + n) * 256 + ci];
        *(bf16x8*)&Bs[sr][sc] = *(const bf16x8*)&WT[(size_t)(n0 + sr) * 1024 + kg];
        __syncthreads();
        bf16x8 a = *(const bf16x8*)&As[w * 16 + lane16][quad * 8];
        #pragma unroll
        for (int ct = 0; ct < 4; ++ct) {
            bf16x8 bb = *(const bf16x8*)&Bs[ct * 16 + lane16][quad * 8];
            acc[ct] = __builtin_amdgcn_mfma_f32_16x16x32_bf16(a, bb, acc[ct], 0, 0, 0);
        }
        __syncthreads();
    }
    #pragma unroll
    for (int ct = 0; ct < 4; ++ct) {
        int col = n0 + ct * 16 + lane16;
        float bv = b2f(bias[col]);
        #pragma unroll
        for (int r = 0; r < 4; ++r) {
            int row = m0 + w * 16 + quad * 4 + r;
            C[(size_t)row * 256 + col] = f2b(acc[ct][r] + bv);
        }
    }
}

// fuseA: blocks where (idx&3)<3 -> qkv (768), (idx&3)==3 -> sr (256).
__global__ __launch_bounds__(256) void fuseA(
    const bf16* __restrict__ cx, const bf16* __restrict__ wTqkv, const bf16* __restrict__ bcat,
    bf16* __restrict__ Cl, bf16* __restrict__ Cq1, bf16* __restrict__ Cq2, bf16* __restrict__ Ckv2,
    const bf16* __restrict__ srwT, const bf16* __restrict__ srb, bf16* __restrict__ xs_pre)
{
    __shared__ __align__(16) char smem[18432];
    int idx = blockIdx.x;
    int g = idx >> 2, r3 = idx & 3;
    if (r3 < 3) {
        int q = g * 3 + r3;           // 0..767
        qkv_body(q & 127, q >> 7, smem, cx, wTqkv, bcat, Cl, Cq1, Cq2, Ckv2);
    } else {
        sr_body(g & 63, g >> 6, smem, cx, srwT, srb, xs_pre);
    }
}

// ---------------------------------------------------------------------------
// layernorm+gelu body, one wave per row (4 ch/lane).
// ---------------------------------------------------------------------------
__device__ __forceinline__ void ln_body(
    int blk,
    const bf16* __restrict__ xin, const bf16* __restrict__ nw,
    const bf16* __restrict__ nb, bf16* __restrict__ xout)
{
    int w = threadIdx.x >> 6, lane = threadIdx.x & 63;
    int r = blk * 4 + w;
    bf16x4 xv = *(const bf16x4*)&xin[(size_t)r * 256 + lane * 4];
    float v[4];
    #pragma unroll
    for (int j = 0; j < 4; ++j) v[j] = s2f(xv[j]);
    float s = v[0] + v[1] + v[2] + v[3];
    #pragma unroll
    for (int o = 1; o <= 32; o <<= 1) s += __shfl_xor(s, o);
    float mean = s * (1.f / 256.f);
    float ss = 0.f;
    #pragma unroll
    for (int j = 0; j < 4; ++j) { float d = v[j] - mean; ss += d * d; }
    #pragma unroll
    for (int o = 1; o <= 32; o <<= 1) ss += __shfl_xor(ss, o);
    float inv = rsqrtf(ss * (1.f / 256.f) + 1e-5f);
    bf16x4 wv = *(const bf16x4*)&nw[lane * 4];
    bf16x4 bv = *(const bf16x4*)&nb[lane * 4];
    bf16 ov[4];
    #pragma unroll
    for (int j = 0; j < 4; ++j) {
        float y = (v[j] - mean) * inv * s2f(wv[j]) + s2f(bv[j]);
        ov[j] = f2b(0.5f * y * (1.f + erff(y * 0.70710678118654752f)));
    }
    *(bf16x4*)&xout[(size_t)r * 256 + lane * 4] = *(bf16x4*)ov;
}

// depthwise 3x3 body, paired rows: one thread -> 8 channels x 2 tokens.
__device__ __forceinline__ void dw_body(
    int blk,
    const bf16* __restrict__ lin, const bf16* __restrict__ dwT,
    const bf16* __restrict__ bias, bf16* __restrict__ out)
{
    int tid = blk * 256 + threadIdx.x;   // 262144
    int c0 = (tid & 31) * 8;
    int j  = (tid >> 5) & 63;
    int i  = ((tid >> 11) & 31) * 2;
    int b  = tid >> 16;
    float acc0[8], acc1[8];
    bf16x8 bv = *(const bf16x8*)&bias[c0];
    #pragma unroll
    for (int q = 0; q < 8; ++q) { acc0[q] = s2f(bv[q]); acc1[q] = s2f(bv[q]); }
    bf16x8 wv[3][3];
    #pragma unroll
    for (int di = 0; di < 3; ++di)
        #pragma unroll
        for (int dj = 0; dj < 3; ++dj)
            wv[di][dj] = *(const bf16x8*)&dwT[(di * 3 + dj) * 256 + c0];
    #pragma unroll
    for (int r = -1; r <= 2; ++r) {
        int ii = i + r;
        if (ii < 0 || ii > 63) continue;
        #pragma unroll
        for (int dj = 0; dj < 3; ++dj) {
            int jj = j + dj - 1;
            if (jj < 0 || jj > 63) continue;
            bf16x8 xv = *(const bf16x8*)&lin[(size_t)((b << 12) + ii * 64 + jj) * 256 + c0];
            if (r <= 1) {
                bf16x8 w0 = wv[r + 1][dj];
                #pragma unroll
                for (int q = 0; q < 8; ++q) acc0[q] += s2f(xv[q]) * s2f(w0[q]);
            }
            if (r >= 0) {
                bf16x8 w1 = wv[r][dj];
                #pragma unroll
                for (int q = 0; q < 8; ++q) acc1[q] += s2f(xv[q]) * s2f(w1[q]);
            }
        }
    }
    bf16 ov[8];
    #pragma unroll
    for (int q = 0; q < 8; ++q) ov[q] = f2b(acc0[q]);
    *(bf16x8*)&out[(size_t)((b << 12) + i * 64 + j) * 256 + c0] = *(bf16x8*)ov;
    #pragma unroll
    for (int q = 0; q < 8; ++q) ov[q] = f2b(acc1[q]);
    *(bf16x8*)&out[(size_t)((b << 12) + (i + 1) * 64 + j) * 256 + c0] = *(bf16x8*)ov;
}

// fuseB: even blocks -> ln_gelu (1024), odd -> dwconv (1024).
__global__ __launch_bounds__(256) void fuseB(
    const bf16* __restrict__ xs_pre, const bf16* __restrict__ nw,
    const bf16* __restrict__ nb, bf16* __restrict__ xs,
    const bf16* __restrict__ lepe_lin, const bf16* __restrict__ dwT,
    const bf16* __restrict__ dwb, bf16* __restrict__ lepe)
{
    int idx = blockIdx.x;
    if ((idx & 1) == 0) ln_body(idx >> 1, xs_pre, nw, nb, xs);
    else                dw_body(idx >> 1, lepe_lin, dwT, dwb, lepe);
}

// ---------------------------------------------------------------------------
// kv1 GEMM body: xs[4096,256] @ kv1_w + b; K-half -> k1, V-half -> v1T.
// smem: As @0 (5120), Bs @5120 (5120).
// ---------------------------------------------------------------------------
__device__ __forceinline__ void kv1_body(
    int bx, int by, char* smem,
    const bf16* __restrict__ A, const bf16* __restrict__ WT, const bf16* __restrict__ bias,
    bf16* __restrict__ k1, bf16* __restrict__ v1T)
{
    bf16 (*As)[40] = (bf16(*)[40])smem;
    bf16 (*Bs)[40] = (bf16(*)[40])(smem + 5120);
    int t = threadIdx.x;
    int m0 = bx * 64, n0 = by * 64;
    int w = t >> 6, l = t & 63, lane16 = l & 15, quad = l >> 4;
    int sr = t >> 2, sc = (t & 3) * 8;
    f32x4 acc[4] = {};
    for (int k0 = 0; k0 < 256; k0 += 32) {
        *(bf16x8*)&As[sr][sc] = *(const bf16x8*)&A[(size_t)(m0 + sr) * 256 + k0 + sc];
        *(bf16x8*)&Bs[sr][sc] = *(const bf16x8*)&WT[(size_t)(n0 + sr) * 256 + k0 + sc];
        __syncthreads();
        bf16x8 a = *(const bf16x8*)&As[w * 16 + lane16][quad * 8];
        #pragma unroll
        for (int ct = 0; ct < 4; ++ct) {
            bf16x8 b = *(const bf16x8*)&Bs[ct * 16 + lane16][quad * 8];
            acc[ct] = __builtin_amdgcn_mfma_f32_16x16x32_bf16(a, b, acc[ct], 0, 0, 0);
        }
        __syncthreads();
    }
    #pragma unroll
    for (int ct = 0; ct < 4; ++ct) {
        int col = n0 + ct * 16 + lane16;
        float bv = b2f(bias[col]);
        #pragma unroll
        for (int r = 0; r < 4; ++r) {
            int row = m0 + w * 16 + quad * 4 + r;
            float val = acc[ct][r] + bv;
            int bb = row >> 10, key = row & 1023;
            if (col < 128) {
                k1[(size_t)row * 128 + col] = f2b(val);
            } else {
                int h = (col - 128) >> 5, ch = (col - 128) & 31;
                v1T[(size_t)((bb * 4 + h) * 32 + ch) * 1024 + key] = f2b(val);
            }
        }
    }
}

// ---------------------------------------------------------------------------
// Branch-2 windowed attention body (r8-validated). smem: PT2 @0 (5120),
// lmw @5120 (64).
// ---------------------------------------------------------------------------
__device__ __forceinline__ void attn2_body(
    int blk, char* smem,
    const bf16* __restrict__ q2, const bf16* __restrict__ kv2,
    bf16* __restrict__ attn_out, float* __restrict__ lm)
{
    bf16* PT2 = (bf16*)smem;
    float* lmw = (float*)(smem + 5120);
    int t = threadIdx.x;
    int b = blk >> 8, win = blk & 255;
    int wi = win >> 4, wj = win & 15;
    int h = t >> 6, l = t & 63, lane16 = l & 15, quad = l >> 4;

    if (t < 16) lmw[t] = 0.f;
    bf16* ptt = PT2 + h * 16 * 40;
    {
        bf16 zz[4] = {};
        *(bf16x4*)&ptt[lane16 * 40 + 16 + quad * 4] = *(bf16x4*)zz;
    }
    __syncthreads();

    size_t base = (size_t)(b * 4096);
    int r0 = wi * 4, c0w = wj * 4;
    int tq = (r0 + (lane16 >> 2)) * 64 + c0w + (lane16 & 3);

    bf16x8 qa = *(const bf16x8*)&q2[(base + tq) * 128 + h * 32 + quad * 8];
    bf16x8 kf = *(const bf16x8*)&kv2[(base + tq) * 256 + h * 32 + quad * 8];

    f32x4 z = {0.f, 0.f, 0.f, 0.f};
    f32x4 sT = __builtin_amdgcn_mfma_f32_16x16x32_bf16(kf, qa, z, 0, 0, 0);
    float sv[4];
    #pragma unroll
    for (int r = 0; r < 4; ++r) sv[r] = sT[r];
    float mx = fmaxf(fmaxf(sv[0], sv[1]), fmaxf(sv[2], sv[3]));
    mx = fmaxf(mx, __shfl_xor(mx, 16));
    mx = fmaxf(mx, __shfl_xor(mx, 32));
    float p[4], lsum = 0.f;
    #pragma unroll
    for (int r = 0; r < 4; ++r) { p[r] = __expf(sv[r] - mx); lsum += p[r]; }
    lsum += __shfl_xor(lsum, 16);
    lsum += __shfl_xor(lsum, 32);
    float rl = 1.f / lsum;
    bf16 pk[4];
    #pragma unroll
    for (int r = 0; r < 4; ++r) { p[r] *= rl; pk[r] = f2b(p[r]); }
    *(bf16x4*)&ptt[lane16 * 40 + quad * 4] = *(bf16x4*)pk;

    bf16x8 vf0 = {}, vf1 = {};
    if (quad < 2) {
        #pragma unroll
        for (int jj = 0; jj < 8; ++jj) {
            int key = quad * 8 + jj;
            int tk = (r0 + (key >> 2)) * 64 + c0w + (key & 3);
            const short* vp = (const short*)&kv2[(base + tk) * 256 + 128 + h * 32];
            vf0[jj] = vp[lane16];
            vf1[jj] = vp[16 + lane16];
        }
    }
    bf16x8 pf = *(const bf16x8*)&ptt[lane16 * 40 + quad * 8];
    f32x4 o0 = __builtin_amdgcn_mfma_f32_16x16x32_bf16(vf0, pf, z, 0, 0, 0);
    f32x4 o1 = __builtin_amdgcn_mfma_f32_16x16x32_bf16(vf1, pf, z, 0, 0, 0);
    {
        bf16 ov0[4], ov1[4];
        #pragma unroll
        for (int r = 0; r < 4; ++r) { ov0[r] = f2b(o0[r]); ov1[r] = f2b(o1[r]); }
        bf16* op = attn_out + (base + tq) * 256 + 128 + h * 32;
        *(bf16x4*)&op[quad * 4]      = *(bf16x4*)ov0;
        *(bf16x4*)&op[16 + quad * 4] = *(bf16x4*)ov1;
    }

    #pragma unroll
    for (int r = 0; r < 4; ++r) {
        float c = p[r];
        c += __shfl_xor(c, 1);
        c += __shfl_xor(c, 2);
        c += __shfl_xor(c, 4);
        c += __shfl_xor(c, 8);
        if (lane16 == 0) atomicAdd(&lmw[quad * 4 + r], c);
    }
    __syncthreads();
    if (t < 16) {
        int nk = (r0 + (t >> 2)) * 64 + c0w + (t & 3);
        lm[(b << 12) + nk] = lmw[t] * (1.f / 64.f);
    }
}

// fuseC2: blocks [0,256) = kv1 GEMM (dispatch-first), [256,1280) = attn2.
// Independent ops (disjoint buffers), both short/high-occupancy — no
// residency-generation trap (combined LDS 10.3KB -> 8 blocks/CU, 2048 cap).
__global__ __launch_bounds__(256) void fuseC2(
    const bf16* __restrict__ xs, const bf16* __restrict__ kv1_wT,
    const bf16* __restrict__ kv1b, bf16* __restrict__ k1, bf16* __restrict__ v1T,
    const bf16* __restrict__ q2, const bf16* __restrict__ kv2,
    bf16* __restrict__ attn_out, float* __restrict__ lm)
{
    __shared__ __align__(16) char smem[10304];
    int idx = blockIdx.x;
    if (idx < 256) kv1_body(idx & 63, idx >> 6, smem, xs, kv1_wT, kv1b, k1, v1T);
    else           attn2_body(idx - 256, smem, q2, kv2, attn_out, lm);
}

// ---------------------------------------------------------------------------
// Branch-1 attention — EXACT r2/r3-measured structure (62.8-63.0 us, x4):
// 1024 blocks x 256 thr, K/V LDS dbuf, 1 barrier/tile, __expf (scale folded
// into q1), PTT[4][16][72]. LDS 32256 B. DO NOT MODIFY: PTT stride 68,
// exp2 variants, shuffle-exchange, big-phase, and all fusions regressed.
// ---------------------------------------------------------------------------
__global__ __launch_bounds__(256) void attn1_split(
    const bf16* __restrict__ q1, const bf16* __restrict__ k1,
    const bf16* __restrict__ v1T, bf16* __restrict__ attn_out, float* __restrict__ g)
{
    __shared__ bf16 Kt[2][64][40];      // double-buffered K tile (key-major)
    __shared__ bf16 Vt[2][32][68];      // double-buffered V^T tile (ch-major)
    __shared__ bf16 PTT[4][16][72];     // per-wave P^T strip [q][k]
    __shared__ float gp[1024];

    int t = threadIdx.x;
    int blk = blockIdx.x;
    int qc = blk & 63, h = (blk >> 6) & 3, b = blk >> 8;
    int n0 = qc * 64;
    int w = t >> 6, l = t & 63, lane16 = l & 15, quad = l >> 4;

    const bf16* Kbase = k1 + (size_t)b * 1024 * 128 + 32 * h;
    const bf16* Vbase = v1T + (size_t)((b * 4 + h) * 32) * 1024;
    bf16x8 qa = *(const bf16x8*)&q1[(size_t)(b * 4096 + n0 + 16 * w + lane16) * 128 + 32 * h + quad * 8];

    for (int i = t; i < 1024; i += 256) gp[i] = 0.f;

    int sr = t >> 2, sc = (t & 3) * 8;      // K staging: 64 rows x 32
    int vrow = t >> 3, vcol = (t & 7) * 8;  // V staging: 32 rows x 64
    bf16* ptt = &PTT[w][0][0];

    // stage tile 0
    *(bf16x8*)&Kt[0][sr][sc]     = *(const bf16x8*)&Kbase[(size_t)sr * 128 + sc];
    *(bf16x8*)&Vt[0][vrow][vcol] = *(const bf16x8*)&Vbase[(size_t)vrow * 1024 + vcol];
    __syncthreads();

    float lacc = 0.f;
    f32x4 oT0 = {}, oT1 = {};

    // ---- sweep 1 over 16 key tiles: 1 barrier/tile, prefetch overlap ----
    for (int ktl = 0; ktl < 16; ++ktl) {
        int cur = ktl & 1;
        bf16x8 knext, vnext;
        if (ktl < 15) {
            knext = *(const bf16x8*)&Kbase[(size_t)((ktl + 1) * 64 + sr) * 128 + sc];
            vnext = *(const bf16x8*)&Vbase[(size_t)vrow * 1024 + (ktl + 1) * 64 + vcol];
        }
        bf16x8 kf[4];
        #pragma unroll
        for (int st = 0; st < 4; ++st)
            kf[st] = *(const bf16x8*)&Kt[cur][st * 16 + lane16][quad * 8];
        #pragma unroll
        for (int st = 0; st < 4; ++st) {
            f32x4 z = {0.f, 0.f, 0.f, 0.f};
            f32x4 sT = __builtin_amdgcn_mfma_f32_16x16x32_bf16(kf[st], qa, z, 0, 0, 0);
            bf16 pk[4];
            #pragma unroll
            for (int r = 0; r < 4; ++r) {
                float p = __expf(sT[r]);
                lacc += p;
                pk[r] = f2b(p);
            }
            *(bf16x4*)&ptt[lane16 * 72 + st * 16 + quad * 4] = *(bf16x4*)pk;
        }
        #pragma unroll
        for (int kh = 0; kh < 2; ++kh) {
            bf16x8 pf  = *(const bf16x8*)&ptt[lane16 * 72 + kh * 32 + quad * 8];
            bf16x8 vf0 = *(const bf16x8*)&Vt[cur][lane16][kh * 32 + quad * 8];
            bf16x8 vf1 = *(const bf16x8*)&Vt[cur][16 + lane16][kh * 32 + quad * 8];
            oT0 = __builtin_amdgcn_mfma_f32_16x16x32_bf16(vf0, pf, oT0, 0, 0, 0);
            oT1 = __builtin_amdgcn_mfma_f32_16x16x32_bf16(vf1, pf, oT1, 0, 0, 0);
        }
        if (ktl < 15) {
            *(bf16x8*)&Kt[cur ^ 1][sr][sc]     = knext;
            *(bf16x8*)&Vt[cur ^ 1][vrow][vcol] = vnext;
        }
        __syncthreads();
    }

    // l for q = lane16 (sum over quads), then normalize + store O
    lacc += __shfl_xor(lacc, 16);
    lacc += __shfl_xor(lacc, 32);
    float rl = 1.f / lacc;
    {
        bf16 ov0[4], ov1[4];
        #pragma unroll
        for (int r = 0; r < 4; ++r) {
            ov0[r] = f2b(oT0[r] * rl);
            ov1[r] = f2b(oT1[r] * rl);
        }
        size_t ro = (size_t)(b * 4096 + n0 + 16 * w + lane16) * 256 + 32 * h;
        *(bf16x4*)&attn_out[ro + quad * 4]      = *(bf16x4*)ov0;
        *(bf16x4*)&attn_out[ro + 16 + quad * 4] = *(bf16x4*)ov1;
    }

    // rl for q = quad*4+r via in-wave shuffle
    float rlq[4];
    #pragma unroll
    for (int r = 0; r < 4; ++r) rlq[r] = __shfl(rl, quad * 4 + r);

    // ---- sweep 2: g column sums; K re-staged via LDS dbuf (coalesced) ----
    *(bf16x8*)&Kt[0][sr][sc] = *(const bf16x8*)&Kbase[(size_t)sr * 128 + sc];
    __syncthreads();
    for (int ktl = 0; ktl < 16; ++ktl) {
        int cur = ktl & 1;
        bf16x8 knext;
        if (ktl < 15)
            knext = *(const bf16x8*)&Kbase[(size_t)((ktl + 1) * 64 + sr) * 128 + sc];
        bf16x8 kf2[4];
        #pragma unroll
        for (int st = 0; st < 4; ++st)
            kf2[st] = *(const bf16x8*)&Kt[cur][st * 16 + lane16][quad * 8];
        #pragma unroll
        for (int st = 0; st < 4; ++st) {
            f32x4 z = {0.f, 0.f, 0.f, 0.f};
            f32x4 s = __builtin_amdgcn_mfma_f32_16x16x32_bf16(qa, kf2[st], z, 0, 0, 0);
            float cs = 0.f;
            #pragma unroll
            for (int r = 0; r < 4; ++r) cs += __expf(s[r]) * rlq[r];
            cs += __shfl_xor(cs, 16);
            cs += __shfl_xor(cs, 32);
            if (quad == 0) atomicAdd(&gp[ktl * 64 + st * 16 + lane16], cs);
        }
        if (ktl < 15)
            *(bf16x8*)&Kt[cur ^ 1][sr][sc] = knext;
        __syncthreads();
    }

    for (int i = t; i < 1024; i += 256)
        atomicAdd(&g[(b << 10) + i], gp[i] * (1.f / 16384.f));
}

// proj GEMM, 128x128 tile: out = 2*((attn+lepe) @ proj_w + bias). grid (128,3);
// y==2 slice handles the mask combine (blockIdx.x < 64).
__global__ __launch_bounds__(256) void gemm_proj128(
    const bf16* __restrict__ A, const bf16* __restrict__ A2,
    const bf16* __restrict__ WT, const bf16* __restrict__ bias,
    const float* __restrict__ lm, const float* __restrict__ g,
    void* __restrict__ dout, const int* __restrict__ flag)
{
    if (blockIdx.y == 2) {
        if (blockIdx.x >= 64) return;
        int tid = blockIdx.x * 256 + threadIdx.x;   // 16384
        int b = tid >> 12, n = tid & 4095;
        int i = n >> 6, j = n & 63;
        float v = lm[tid] + g[(b << 10) + (i >> 1) * 32 + (j >> 1)];
        size_t o1 = (size_t)4194304 + (b << 12) + i * 64 + j;
        size_t o2 = (size_t)4194304 + 16384 + (b << 12) + j * 64 + i;
        if (*flag) { ((float*)dout)[o1] = v; ((float*)dout)[o2] = v; }
        else       { ((bf16*)dout)[o1] = f2b(v); ((bf16*)dout)[o2] = f2b(v); }
        return;
    }
    __shared__ bf16 As[128][40];
    __shared__ bf16 Bs[128][40];
    int t = threadIdx.x;
    int m0 = blockIdx.x * 128, n0 = blockIdx.y * 128;
    int w = t >> 6, l = t & 63, lane16 = l & 15, quad = l >> 4;
    int wr = w >> 1, wc = w & 1;
    int sr = t >> 1, sc = (t & 1) * 16;
    f32x4 acc[4][4] = {};
    for (int k0 = 0; k0 < 256; k0 += 32) {
        #pragma unroll
        for (int hh = 0; hh < 2; ++hh) {
            bf16x8 va = *(const bf16x8*)&A[(size_t)(m0 + sr) * 256 + k0 + sc + hh * 8];
            bf16x8 vb = *(const bf16x8*)&A2[(size_t)(m0 + sr) * 256 + k0 + sc + hh * 8];
            bf16 tmp[8];
            #pragma unroll
            for (int q = 0; q < 8; ++q) tmp[q] = f2b(s2f(va[q]) + s2f(vb[q]));
            *(bf16x8*)&As[sr][sc + hh * 8] = *(bf16x8*)tmp;
        }
        *(bf16x8*)&Bs[sr][sc]     = *(const bf16x8*)&WT[(size_t)(n0 + sr) * 256 + k0 + sc];
        *(bf16x8*)&Bs[sr][sc + 8] = *(const bf16x8*)&WT[(size_t)(n0 + sr) * 256 + k0 + sc + 8];
        __syncthreads();
        bf16x8 a[4], b[4];
        #pragma unroll
        for (int i = 0; i < 4; ++i) {
            a[i] = *(const bf16x8*)&As[wr * 64 + i * 16 + lane16][quad * 8];
            b[i] = *(const bf16x8*)&Bs[wc * 64 + i * 16 + lane16][quad * 8];
        }
        #pragma unroll
        for (int i = 0; i < 4; ++i)
            #pragma unroll
            for (int j = 0; j < 4; ++j)
                acc[i][j] = __builtin_amdgcn_mfma_f32_16x16x32_bf16(a[i], b[j], acc[i][j], 0, 0, 0);
        __syncthreads();
    }
    #pragma unroll
    for (int j = 0; j < 4; ++j) {
        int col = n0 + wc * 64 + j * 16 + lane16;
        float bv = b2f(bias[col]);
        #pragma unroll
        for (int i = 0; i < 4; ++i)
            #pragma unroll
            for (int r = 0; r < 4; ++r) {
                int row = m0 + wr * 64 + i * 16 + quad * 4 + r;
                float rv = (acc[i][j][r] + bv) * 2.f;
                size_t o = (size_t)row * 256 + col;
                if (*flag) ((float*)dout)[o] = rv;
                else       ((bf16*)dout)[o] = f2b(rv);
            }
    }
}

// ---------------------------------------------------------------------------
extern "C" void kernel_launch(void* const* d_in, const int* in_sizes, int n_in,
                              void* d_out, int out_size, void* d_ws, size_t ws_size,
                              hipStream_t stream)
{
    char* ws = (char*)d_ws;
    size_t off = 0;
    auto alloc = [&](size_t bytes) {
        void* p = ws + off;
        off += (bytes + 255) & ~(size_t)255;
        return p;
    };
    bf16* cx       = (bf16*)alloc((size_t)4194304 * 2);
    bf16* lepe_lin = (bf16*)alloc((size_t)4194304 * 2);   // reused as attn_out
    bf16* attn_out = lepe_lin;
    bf16* lepe     = (bf16*)alloc((size_t)4194304 * 2);
    bf16* q1buf    = (bf16*)alloc((size_t)2097152 * 2);
    bf16* q2buf    = (bf16*)alloc((size_t)2097152 * 2);
    bf16* kv2buf   = (bf16*)alloc((size_t)4194304 * 2);
    bf16* xs_pre   = (bf16*)alloc((size_t)1048576 * 2);   // later reused: k1 + v1T
    bf16* k1buf    = xs_pre;                               // 524288 elems
    bf16* v1Tbuf   = xs_pre + 524288;                      // 524288 elems
    bf16* xs       = (bf16*)alloc((size_t)1048576 * 2);
    bf16* wTqkv    = (bf16*)alloc((size_t)196608 * 2);     // 768 x 256
    bf16* kv1_wT   = (bf16*)alloc(65536 * 2);
    bf16* proj_wT  = (bf16*)alloc(65536 * 2);
    bf16* sr_wT    = (bf16*)alloc(262144 * 2);
    bf16* dwT      = (bf16*)alloc(2304 * 2);
    bf16* bcat     = (bf16*)alloc(768 * 2);
    bf16* ckv1b    = (bf16*)alloc(256 * 2);
    bf16* csrb     = (bf16*)alloc(256 * 2);
    bf16* cnw      = (bf16*)alloc(256 * 2);
    bf16* cnb      = (bf16*)alloc(256 * 2);
    bf16* cpb      = (bf16*)alloc(256 * 2);
    bf16* clcb     = (bf16*)alloc(256 * 2);
    float* gbuf    = (float*)alloc(4096 * 4);
    float* lmbuf   = (float*)alloc(16384 * 4);
    int*   flag    = (int*)alloc(256);

    detect_dtype<<<1, 256, 0, stream>>>(d_in[0], flag);

    AllArgs aa;
    aa.x = d_in[0]; aa.cx = cx;
    aa.srw = d_in[13]; aa.srwT = sr_wT;
    aa.dww = d_in[11]; aa.dwT = dwT;
    aa.psrc[0] = d_in[10]; aa.pdst[0] = bcat;       aa.pn[0] = 256;  // lepe_b
    aa.psrc[1] = d_in[2];  aa.pdst[1] = bcat + 256; aa.pn[1] = 128;  // q1_b
    aa.psrc[2] = d_in[6];  aa.pdst[2] = bcat + 384; aa.pn[2] = 128;  // q2_b
    aa.psrc[3] = d_in[8];  aa.pdst[3] = bcat + 512; aa.pn[3] = 256;  // kv2_b
    aa.psrc[4] = d_in[4];  aa.pdst[4] = ckv1b;      aa.pn[4] = 256;
    aa.psrc[5] = d_in[14]; aa.pdst[5] = csrb;       aa.pn[5] = 256;
    aa.psrc[6] = d_in[15]; aa.pdst[6] = cnw;        aa.pn[6] = 256;
    aa.psrc[7] = d_in[16]; aa.pdst[7] = cnb;        aa.pn[7] = 256;
    aa.psrc[8] = d_in[18]; aa.pdst[8] = cpb;        aa.pn[8] = 256;
    aa.psrc[9] = d_in[12]; aa.pdst[9] = clcb;       aa.pn[9] = 256;
    aa.wsrc[0] = d_in[9];  aa.wdst[0] = wTqkv;             aa.wN[0] = 256;
    aa.wsrc[1] = d_in[1];  aa.wdst[1] = wTqkv + 256 * 256; aa.wN[1] = 128;
    aa.wsrc[2] = d_in[5];  aa.wdst[2] = wTqkv + 384 * 256; aa.wN[2] = 128;
    aa.wsrc[3] = d_in[7];  aa.wdst[3] = wTqkv + 512 * 256; aa.wN[3] = 256;
    aa.wsrc[4] = d_in[3];  aa.wdst[4] = kv1_wT;            aa.wN[4] = 256;
    aa.wsrc[5] = d_in[17]; aa.wdst[5] = proj_wT;           aa.wN[5] = 256;
    int bo[7] = {0, 256, 384, 512, 768, 1024, 1280};
    for (int i = 0; i < 7; ++i) aa.wblkoff[i] = bo[i];
    aa.gbuf = gbuf;
    convert_all<<<6420, 256, 0, stream>>>(aa, flag);

    // fuseA: qkv projections (768 blocks, gl_lds B staging) + sr conv (256)
    fuseA<<<1024, 256, 0, stream>>>(cx, wTqkv, bcat, lepe_lin, q1buf, q2buf, kv2buf,
                                    sr_wT, csrb, xs_pre);
    // fuseB: ln+gelu (1024) + depthwise conv (1024), interleaved
    fuseB<<<2048, 256, 0, stream>>>(xs_pre, cnw, cnb, xs, lepe_lin, dwT, clcb, lepe);
    // fuseC2: kv1 GEMM (256 blocks) + attn2 (1024 blocks) — independent ops
    fuseC2<<<1280, 256, 0, stream>>>(xs, kv1_wT, ckv1b, k1buf, v1Tbuf,
                                     q2buf, kv2buf, attn_out, lmbuf);
    // attn1: own launch, exact validated structure (never co-schedule)
    attn1_split<<<1024, 256, 0, stream>>>(q1buf, k1buf, v1Tbuf, attn_out, gbuf);
    // projection epilogue (128x128 tile) + fused mask combine (y==2 slice)
    gemm_proj128<<<dim3(128, 3), 256, 0, stream>>>(attn_out, lepe, proj_wT, cpb,
                                                   lmbuf, gbuf, d_out, flag);
}